// Round 6
// baseline (93.559 us; speedup 1.0000x reference)
//
#include <hip/hip_runtime.h>

// PixelVectorExtractor: x (32,16,128,128) f32 ->
// out (32, 16384, 17, 9) f32 where out[n][h*128+w][c][hl*3+wl] =
//   c==16 ? 1.0f : zero-padded x[n][c][h+hl-1][w+wl-1]
//
// One block (320 thr) per (n, h-pair). Stage input rows h0-1..h0+2 of 16
// channels in bank-skewed LDS + a small all-ones window. Each of 306 active
// threads owns a fixed (slab, qm) slot of the 612-element repeating output
// pattern; its 4 LDS source offsets are computed ONCE into registers, then a
// fully-unrolled g-loop does 4x ds_read_b32 (immediate offsets) + 1 NT
// float4 store per pixel-group. No per-iter divides, no descriptor reads.

#define NN 32
#define CC 16
#define HH 128
#define WW 128
#define RSTRIDE 140              // floats per (c,hr) row (mod 32 = 12)
#define CSTRIDE 564              // floats per channel (mod 32 = 20)
#define ONES_OFF (16 * CSTRIDE)  // 9024: 266-float all-ones window
#define NFLOATS (ONES_OFF + 266) // 9290 floats = 37160 B

typedef float f4 __attribute__((ext_vector_type(4)));

__global__ __launch_bounds__(320) void pve_kernel(const float* __restrict__ x,
                                                  float* __restrict__ out) {
    __shared__ float lds[NFLOATS];

    // bijective XCD swizzle: 2048 blocks, 8 XCDs, 256 contiguous per XCD
    unsigned bid = blockIdx.x;
    unsigned swz = (bid & 7u) * 256u + (bid >> 3);
    unsigned n = swz >> 6;    // image
    unsigned hp = swz & 63u;  // row pair
    unsigned h0 = hp * 2u;
    unsigned tid = threadIdx.x;

    // all-ones window (ones-channel descriptors alias into it)
    if (tid < 266u) lds[ONES_OFF + tid] = 1.0f;

    // zero halo pads of the 64 real (c,hr) rows
    if (tid < 64u) {
        unsigned c = tid >> 2, hr = tid & 3u;
        lds[c * CSTRIDE + hr * RSTRIDE + 3] = 0.0f;
        lds[c * CSTRIDE + hr * RSTRIDE + 132] = 0.0f;
    }

    // stage: 64 rows x 32 float4 = 2048 float4, coalesced
#pragma unroll
    for (int j = 0; j < 7; ++j) {
        unsigned li = tid + 320u * j;
        if (li < 2048u) {
            unsigned row = li >> 5;  // 0..63 = c*4 + hr
            unsigned col = li & 31u;
            unsigned c = row >> 2;
            unsigned hr = row & 3u;
            int hh = (int)h0 + (int)hr - 1;
            f4 v = {0.f, 0.f, 0.f, 0.f};
            if ((unsigned)hh < (unsigned)HH) {
                v = reinterpret_cast<const f4*>(
                        x)[((n * CC + c) * HH + (unsigned)hh) * (WW / 4) + col];
            }
            *reinterpret_cast<f4*>(
                &lds[c * CSTRIDE + hr * RSTRIDE + 4u + col * 4u]) = v;
        }
    }

    // per-thread constant descriptors: thread -> (s, qm), qm in [0,153)
    unsigned qm = (tid < 153u) ? tid : tid - 153u;
    unsigned s = (tid < 153u) ? 0u : 1u;
    bool active = (tid < 306u);

    unsigned fbase[4];
#pragma unroll
    for (int k = 0; k < 4; ++k) {
        unsigned ii = qm * 4u + (unsigned)k;  // 0..611 = (dw*17 + c)*9 + p
        unsigned p = ii % 9u;
        unsigned t = ii / 9u;
        unsigned c = t % 17u;
        unsigned dw = t / 17u;
        unsigned hl = p / 3u;
        unsigned wl = p - hl * 3u;
        unsigned fi = (c < 16u) ? (c * CSTRIDE + hl * RSTRIDE + 3u + wl + dw)
                                : (unsigned)ONES_OFF;
        fbase[k] = fi + s * RSTRIDE;  // slab shift = one h-row = RSTRIDE
    }

    __syncthreads();

    if (active) {
        // slab quad base: ((n*16384 + (h0+s)*128) * 153) / 4
        unsigned qbase = n * 626688u + (h0 + s) * 4896u + qm;
        f4* outp = reinterpret_cast<f4*>(out);
#pragma unroll
        for (unsigned g = 0; g < 32u; ++g) {
            f4 v;
            v.x = lds[fbase[0] + g * 4u];
            v.y = lds[fbase[1] + g * 4u];
            v.z = lds[fbase[2] + g * 4u];
            v.w = lds[fbase[3] + g * 4u];
            __builtin_nontemporal_store(v, &outp[qbase + g * 153u]);
        }
    }
}

extern "C" void kernel_launch(void* const* d_in, const int* in_sizes, int n_in,
                              void* d_out, int out_size, void* d_ws, size_t ws_size,
                              hipStream_t stream) {
    const float* x = (const float*)d_in[0];
    float* out = (float*)d_out;
    pve_kernel<<<NN * HH / 2, 320, 0, stream>>>(x, out);
}

// Round 7
// 76.404 us; speedup vs baseline: 1.2245x; 1.2245x over previous
//
#include <hip/hip_runtime.h>

// PixelVectorExtractor: x (32,16,128,128) f32 ->
// out (32, 16384, 17, 9) f32 where out[n][h*128+w][c][hl*3+wl] =
//   c==16 ? 1.0f : zero-padded x[n][c][h+hl-1][w+wl-1]
//
// R5 structure (best: 67.9 us), single change: regular stores instead of
// nontemporal (A/B on the L2 write path; memset calibrates 7 TB/s w/ L2).
//
// One block per (n, h-pair). Stage rows h0-1..h0+2 of 16 channels in LDS
// (bank-skewed layout) plus a materialized all-ones channel 16. Epilogue
// reads u32 byte-offset descriptors (pattern repeats every 612 outputs =
// 4 pixels) and does uniform add+ds_read_b32 per value -> float4 store.

#define NN 32
#define CC 16
#define HH 128
#define WW 128
#define RSTRIDE 140              // floats per (c,hr) row (mod 32 = 12)
#define CSTRIDE 564              // floats per channel (mod 32 = 20)
#define NFLOATS (17 * CSTRIDE)   // 9588 floats = 38352 B

typedef float f4 __attribute__((ext_vector_type(4)));

__global__ __launch_bounds__(256) void pve_kernel(const float* __restrict__ x,
                                                  float* __restrict__ out) {
    __shared__ float lds[NFLOATS];
    __shared__ unsigned desc[612];  // byte offsets, 2448 B

    // bijective XCD swizzle: 2048 blocks, 8 XCDs, 256 contiguous per XCD
    unsigned bid = blockIdx.x;
    unsigned swz = (bid & 7u) * 256u + (bid >> 3);
    unsigned n = swz >> 6;    // image
    unsigned hp = swz & 63u;  // row pair
    unsigned h0 = hp * 2u;
    unsigned tid = threadIdx.x;

    // descriptor table (block-invariant): ii = (dw*17 + c)*9 + p,
    // value = byte offset of (c, hl, 3 + wl + dw); add g*16 + s*560 at use.
    for (unsigned ii = tid; ii < 612u; ii += 256u) {
        unsigned p = ii % 9u;
        unsigned t = ii / 9u;
        unsigned c = t % 17u;
        unsigned dw = t / 17u;
        unsigned hl = p / 3u;
        unsigned wl = p - hl * 3u;
        desc[ii] = (c * CSTRIDE + hl * RSTRIDE + 3u + wl + dw) * 4u;
    }

    // ones channel: fill channel 16 region with 1.0f
    for (unsigned li = tid; li < CSTRIDE; li += 256u)
        lds[16u * CSTRIDE + li] = 1.0f;

    // zero halo pads of the 64 real (c,hr) rows
    if (tid < 64u) {
        unsigned c = tid >> 2, hr = tid & 3u;
        lds[c * CSTRIDE + hr * RSTRIDE + 3] = 0.0f;
        lds[c * CSTRIDE + hr * RSTRIDE + 132] = 0.0f;
    }

    // stage: 64 rows x 32 float4 = 2048 float4, 8 per thread, coalesced
#pragma unroll
    for (int j = 0; j < 8; ++j) {
        unsigned li = tid + 256u * j;  // 0..2047
        unsigned row = li >> 5;        // 0..63 = c*4 + hr
        unsigned col = li & 31u;       // float4 column
        unsigned c = row >> 2;
        unsigned hr = row & 3u;
        int hh = (int)h0 + (int)hr - 1;
        f4 v = {0.f, 0.f, 0.f, 0.f};
        if ((unsigned)hh < (unsigned)HH) {
            v = reinterpret_cast<const f4*>(
                    x)[((n * CC + c) * HH + (unsigned)hh) * (WW / 4) + col];
        }
        *reinterpret_cast<f4*>(&lds[c * CSTRIDE + hr * RSTRIDE + 4u + col * 4u]) = v;
    }
    __syncthreads();

    const char* ldsb = reinterpret_cast<const char*>(lds);

    // two slabs of 4896 float4 each (32 groups of 153), contiguous stores
#pragma unroll
    for (unsigned s = 0; s < 2u; ++s) {
        unsigned base = (n * 16384u + (h0 + s) * 128u) * 153u;
        f4* outp = reinterpret_cast<f4*>(out + base);
        unsigned sofs = s * (RSTRIDE * 4u);  // slab row shift, bytes
#pragma unroll 2
        for (unsigned q = tid; q < 4896u; q += 256u) {
            unsigned g = q / 153u;  // 4-pixel group (0..31)
            unsigned qm = q - g * 153u;
            unsigned wo = g * 16u + sofs;  // byte offset add-on
            uint4 d4 = *reinterpret_cast<const uint4*>(&desc[qm * 4u]);
            f4 v;
            v.x = *reinterpret_cast<const float*>(ldsb + (d4.x + wo));
            v.y = *reinterpret_cast<const float*>(ldsb + (d4.y + wo));
            v.z = *reinterpret_cast<const float*>(ldsb + (d4.z + wo));
            v.w = *reinterpret_cast<const float*>(ldsb + (d4.w + wo));
            outp[q] = v;
        }
    }
}

extern "C" void kernel_launch(void* const* d_in, const int* in_sizes, int n_in,
                              void* d_out, int out_size, void* d_ws, size_t ws_size,
                              hipStream_t stream) {
    const float* x = (const float*)d_in[0];
    float* out = (float*)d_out;
    pve_kernel<<<NN * HH / 2, 256, 0, stream>>>(x, out);
}

// Round 8
// 65.808 us; speedup vs baseline: 1.4217x; 1.1610x over previous
//
#include <hip/hip_runtime.h>

// PixelVectorExtractor: x (32,16,128,128) f32 ->
// out (32, 16384, 17, 9) f32 where out[n][h*128+w][c][hl*3+wl] =
//   c==16 ? 1.0f : zero-padded x[n][c][h+hl-1][w+wl-1]
//
// R5 structure + NT stores (A/B-proven best) + fused slab loop: one
// descriptor read feeds both output rows (two independent LDS-read->store
// chains per iteration -> 2x ILP, 25% less LDS traffic).
//
// One block per (n, h-pair). Stage rows h0-1..h0+2 of 16 channels in LDS
// (bank-skewed layout) plus a materialized all-ones channel 16.

#define NN 32
#define CC 16
#define HH 128
#define WW 128
#define RSTRIDE 140              // floats per (c,hr) row (mod 32 = 12)
#define CSTRIDE 564              // floats per channel (mod 32 = 20)
#define NFLOATS (17 * CSTRIDE)   // 9588 floats = 38352 B

typedef float f4 __attribute__((ext_vector_type(4)));

__global__ __launch_bounds__(256) void pve_kernel(const float* __restrict__ x,
                                                  float* __restrict__ out) {
    __shared__ float lds[NFLOATS];
    __shared__ unsigned desc[612];  // byte offsets, 2448 B

    // bijective XCD swizzle: 2048 blocks, 8 XCDs, 256 contiguous per XCD
    unsigned bid = blockIdx.x;
    unsigned swz = (bid & 7u) * 256u + (bid >> 3);
    unsigned n = swz >> 6;    // image
    unsigned hp = swz & 63u;  // row pair
    unsigned h0 = hp * 2u;
    unsigned tid = threadIdx.x;

    // descriptor table (block-invariant): ii = (dw*17 + c)*9 + p,
    // value = byte offset of (c, hl, 3 + wl + dw); add g*16 (+560 slab1).
    for (unsigned ii = tid; ii < 612u; ii += 256u) {
        unsigned p = ii % 9u;
        unsigned t = ii / 9u;
        unsigned c = t % 17u;
        unsigned dw = t / 17u;
        unsigned hl = p / 3u;
        unsigned wl = p - hl * 3u;
        desc[ii] = (c * CSTRIDE + hl * RSTRIDE + 3u + wl + dw) * 4u;
    }

    // ones channel: fill channel 16 region with 1.0f
    for (unsigned li = tid; li < CSTRIDE; li += 256u)
        lds[16u * CSTRIDE + li] = 1.0f;

    // zero halo pads of the 64 real (c,hr) rows
    if (tid < 64u) {
        unsigned c = tid >> 2, hr = tid & 3u;
        lds[c * CSTRIDE + hr * RSTRIDE + 3] = 0.0f;
        lds[c * CSTRIDE + hr * RSTRIDE + 132] = 0.0f;
    }

    // stage: 64 rows x 32 float4 = 2048 float4, 8 per thread, coalesced
#pragma unroll
    for (int j = 0; j < 8; ++j) {
        unsigned li = tid + 256u * j;  // 0..2047
        unsigned row = li >> 5;        // 0..63 = c*4 + hr
        unsigned col = li & 31u;       // float4 column
        unsigned c = row >> 2;
        unsigned hr = row & 3u;
        int hh = (int)h0 + (int)hr - 1;
        f4 v = {0.f, 0.f, 0.f, 0.f};
        if ((unsigned)hh < (unsigned)HH) {
            v = reinterpret_cast<const f4*>(
                    x)[((n * CC + c) * HH + (unsigned)hh) * (WW / 4) + col];
        }
        *reinterpret_cast<f4*>(&lds[c * CSTRIDE + hr * RSTRIDE + 4u + col * 4u]) = v;
    }
    __syncthreads();

    const char* ldsb = reinterpret_cast<const char*>(lds);

    // fused epilogue: 4896 float4 positions, each written to BOTH slabs
    unsigned base0 = (n * 16384u + h0 * 128u) * 153u;
    f4* outp0 = reinterpret_cast<f4*>(out + base0);
    f4* outp1 = outp0 + 4896u;  // slab 1 = next h row, contiguous after
#pragma unroll 2
    for (unsigned q = tid; q < 4896u; q += 256u) {
        unsigned g = q / 153u;  // 4-pixel group (0..31)
        unsigned qm = q - g * 153u;
        unsigned wo = g * 16u;  // byte offset add-on, slab 0
        uint4 d4 = *reinterpret_cast<const uint4*>(&desc[qm * 4u]);
        f4 v0, v1;
        v0.x = *reinterpret_cast<const float*>(ldsb + (d4.x + wo));
        v0.y = *reinterpret_cast<const float*>(ldsb + (d4.y + wo));
        v0.z = *reinterpret_cast<const float*>(ldsb + (d4.z + wo));
        v0.w = *reinterpret_cast<const float*>(ldsb + (d4.w + wo));
        unsigned wo1 = wo + (RSTRIDE * 4u);  // slab 1: one h-row down
        v1.x = *reinterpret_cast<const float*>(ldsb + (d4.x + wo1));
        v1.y = *reinterpret_cast<const float*>(ldsb + (d4.y + wo1));
        v1.z = *reinterpret_cast<const float*>(ldsb + (d4.z + wo1));
        v1.w = *reinterpret_cast<const float*>(ldsb + (d4.w + wo1));
        __builtin_nontemporal_store(v0, &outp0[q]);
        __builtin_nontemporal_store(v1, &outp1[q]);
    }
}

extern "C" void kernel_launch(void* const* d_in, const int* in_sizes, int n_in,
                              void* d_out, int out_size, void* d_ws, size_t ws_size,
                              hipStream_t stream) {
    const float* x = (const float*)d_in[0];
    float* out = (float*)d_out;
    pve_kernel<<<NN * HH / 2, 256, 0, stream>>>(x, out);
}